// Round 7
// baseline (168.968 us; speedup 1.0000x reference)
//
#include <hip/hip_runtime.h>
#include <cstdint>

typedef __attribute__((ext_vector_type(8))) _Float16 half8;
typedef __attribute__((ext_vector_type(4))) _Float16 half4;
typedef __attribute__((ext_vector_type(2))) _Float16 half2v;
typedef __attribute__((ext_vector_type(16))) float f32x16;
typedef __attribute__((ext_vector_type(4))) float f4;

#define LOG2E 1.44269504088896340f
#define KNL  (-1.44269504088896340f)

__device__ __forceinline__ float fast_exp(float x) { return __builtin_amdgcn_exp2f(LOG2E * x); }
__device__ __forceinline__ float sigmoidf(float v) {
    return __builtin_amdgcn_rcpf(1.f + __builtin_amdgcn_exp2f(KNL * v));
}
// sigmoid where the -log2e factor is already folded into the argument
__device__ __forceinline__ float sig2(float y) {
    return __builtin_amdgcn_rcpf(1.f + __builtin_amdgcn_exp2f(y));
}
__device__ __forceinline__ unsigned pk2(float a, float b) {
    half2v h = { (_Float16)a, (_Float16)b };   // RNE
    return __builtin_bit_cast(unsigned, h);
}
__device__ __forceinline__ void swapl(unsigned& a, unsigned& b) {
    asm volatile("v_permlane32_swap_b32 %0, %1" : "+v"(a), "+v"(b));
}
__device__ __forceinline__ void swaplf(float& a, float& b) {
    asm volatile("v_permlane32_swap_b32 %0, %1" : "+v"(a), "+v"(b));
}
union BU { unsigned u[4]; half8 h; };

// CgF const region (f32 indices). A0X/A0T/B0O and BMO are KNL-prescaled.
constexpr int A0X = 0, A0T = 128, B0O = 256, BMO = 384, VLO = 1152,
              W1P = 1280, B1P = 1344, B2P = 1408, W3P = 1472, CN = 1536;

// ws byte offsets
constexpr int GHIO  = 0;                  // 6 x 32768 fp16 hi, KNL-scaled, swizzled
constexpr int GLOO  = 6 * 32768;          // 6 x 32768 fp16 lo, KNL-scaled, plain rows
constexpr int W2HIO = 12 * 32768;         // 8192
constexpr int W2LOO = W2HIO + 8192;       // 8192
constexpr int CGOFF = W2LOO + 8192;       // CN*4

// ---------------- fused prep: 97 blocks x 256 threads ----------------
// Blocks 0..95 (l = b>>4, q = b&15): rows [8q,8q+8) of M_l = A_{l+1}*W_l, fp32,
// scaled by KNL, split fp16 hi/lo. hi written swizzled ((r&15)<<4), lo plain.
// Block 96: vL = W6^T uLs, first-layer consts (KNL-scaled), MLP consts, W2 hi/lo.
__global__ __launch_bounds__(256)
void prep_kernel(const float* __restrict__ u0, const float* __restrict__ w0,
                 const float* __restrict__ la0, const float* __restrict__ b0,
                 const float* __restrict__ uM, const float* __restrict__ wM,
                 const float* __restrict__ laM, const float* __restrict__ bM,
                 const float* __restrict__ uL, const float* __restrict__ laL,
                 const float* __restrict__ W1, const float* __restrict__ b1,
                 const float* __restrict__ W2, const float* __restrict__ b2,
                 const float* __restrict__ W3,
                 char* __restrict__ Ghi, char* __restrict__ Glo,
                 _Float16* __restrict__ W2hi, _Float16* __restrict__ W2lo,
                 float* __restrict__ CgF)
{
    __shared__ float Wl[128 * 136];   // softmaxed W_l
    __shared__ float Al[8 * 132];     // scaled-softmaxed A rows
    __shared__ float uls[128];

    const int tid = threadIdx.x, b = blockIdx.x;
    const bool mblk = (b < 96);
    const int l = mblk ? (b >> 4) : 6;

    // ---- step 1: row-softmax W_l into LDS ----
    {
        const float* Wsrc = (l == 0) ? w0 : wM + (l - 1) * 16384;
        const int r = tid >> 1, h = tid & 1;
        const float* rp = Wsrc + r * 128 + h * 64;
        f4 buf[16];
#pragma unroll
        for (int v = 0; v < 16; ++v) buf[v] = *(const f4*)(rp + 4 * v);
        float mx = -1e30f;
#pragma unroll
        for (int v = 0; v < 16; ++v)
#pragma unroll
            for (int e = 0; e < 4; ++e) mx = fmaxf(mx, buf[v][e]);
        mx = fmaxf(mx, __shfl_xor(mx, 1));
        float s = 0.f;
#pragma unroll
        for (int v = 0; v < 16; ++v)
#pragma unroll
            for (int e = 0; e < 4; ++e) { buf[v][e] = fast_exp(buf[v][e] - mx); s += buf[v][e]; }
        s += __shfl_xor(s, 1);
        float inv = 1.f / s;
#pragma unroll
        for (int v = 0; v < 16; ++v)
            *(f4*)(&Wl[r * 136 + h * 64 + 4 * v]) = buf[v] * inv;
    }

    if (mblk) {
        const int q = b & 15;
        const int rl = tid >> 5, part = tid & 31;   // 8 rows x 32 threads
        const int gi = q * 8 + rl;
        // ---- step 2: A row gi = exp(laM)*softmax(uM row) ----
        {
            f4 ub = *(const f4*)(uM + (l * 128 + gi) * 128 + part * 4);
            float mx = fmaxf(fmaxf(ub[0], ub[1]), fmaxf(ub[2], ub[3]));
#pragma unroll
            for (int o = 1; o < 32; o <<= 1) mx = fmaxf(mx, __shfl_xor(mx, o));
            float s = 0.f;
#pragma unroll
            for (int e = 0; e < 4; ++e) { ub[e] = fast_exp(ub[e] - mx); s += ub[e]; }
#pragma unroll
            for (int o = 1; o < 32; o <<= 1) s += __shfl_xor(s, o);
            float sc = fast_exp(laM[l * 128 + gi]) / s;
            *(f4*)(&Al[rl * 132 + part * 4]) = ub * sc;
        }
        __syncthreads();
        // ---- step 3: 4 output cols per thread ----
        const int j0 = part * 4;
        f4 acc = {};
        for (int k = 0; k < 128; ++k) {
            float a = Al[rl * 132 + k];
            acc += a * *(const f4*)(&Wl[k * 136 + j0]);
        }
        // ---- step 4: KNL-scale, split hi/lo, store ----
        const int sw = (gi & 15) << 4;
        char* bh = Ghi + l * 32768 + gi * 256;
        char* bl = Glo + l * 32768 + gi * 256;
        half4 hv, lv;
#pragma unroll
        for (int e = 0; e < 4; ++e) {
            float m = KNL * acc[e];
            _Float16 hh = (_Float16)m;
            hv[e] = hh;
            lv[e] = (_Float16)(m - (float)hh);
        }
        *(half4*)(bh + ((2 * j0) ^ sw)) = hv;
        *(half4*)(bl + 2 * j0) = lv;
    } else {
        // ---- misc block ----
        if (tid < 64) {
            float v0 = uL[tid], v1 = uL[tid + 64];
            float mx = fmaxf(v0, v1);
#pragma unroll
            for (int o = 32; o; o >>= 1) mx = fmaxf(mx, __shfl_xor(mx, o));
            float e0 = fast_exp(v0 - mx), e1 = fast_exp(v1 - mx);
            float ssum = e0 + e1;
#pragma unroll
            for (int o = 32; o; o >>= 1) ssum += __shfl_xor(ssum, o);
            float aL = fast_exp(laL[0]) / ssum;
            uls[tid]      = e0 * aL;
            uls[tid + 64] = e1 * aL;
        }
        __syncthreads();
        if (tid < 128) {
            float s = 0.f;
            for (int k = 0; k < 128; ++k) s += uls[k] * Wl[k * 136 + tid];
            CgF[VLO + tid] = s;
        }
        if (tid < 128) {
            const int j = tid;
            float q0 = u0[2 * j], q1 = u0[2 * j + 1];
            float mx = fmaxf(q0, q1);
            float e0 = fast_exp(q0 - mx), e1 = fast_exp(q1 - mx);
            float a = fast_exp(la0[j]) / (e0 + e1);
            CgF[A0X + j] = KNL * a * e0;
            CgF[A0T + j] = KNL * a * e1;
            CgF[B0O + j] = KNL * b0[j];
        } else if (tid < 192) {
            const int t = tid - 128;
            CgF[W1P + t] = (t < 50) ? W1[t] : 0.f;
            CgF[B1P + t] = (t < 50) ? b1[t] : 0.f;
            CgF[B2P + t] = (t < 50) ? b2[t] : 0.f;
            CgF[W3P + t] = (t < 50) ? W3[t] : 0.f;
        }
        for (int i = tid; i < 768; i += 256) CgF[BMO + i] = KNL * bM[i];
        for (int i = tid; i < 4096; i += 256) {
            int r = i >> 6, c = i & 63;
            float v = (r < 50 && c < 50) ? W2[r * 50 + c] : 0.f;
            _Float16 h = (_Float16)v;
            W2hi[i] = h;
            W2lo[i] = (_Float16)(v - (float)h);
        }
    }
}

// ---------------- main ----------------
// 512 blocks x 256 threads (4 waves, 64 batch/wave), 2 blocks/CU (64KB LDS each).
// hi-matrix: HBM -> LDS dbuf (global_load_lds, swizzled image). lo-matrix:
// per-lane global loads (L1/L2-cached). Activations register-resident.

__device__ __forceinline__ void stage32(char* ls, const char* gs, int tid) {
#pragma unroll
    for (int i = 0; i < 8; ++i)
        __builtin_amdgcn_global_load_lds(
            (const __attribute__((address_space(1))) unsigned*)(uintptr_t)(gs + tid * 16 + i * 4096),
            (__attribute__((address_space(3))) unsigned*)(uintptr_t)(ls + tid * 16 + i * 4096),
            16, 0, 0);
}

// acc already contains KNL*(Wx+b); sigmoid = rcp(1+exp2(acc))
__device__ __forceinline__ void epi_nt(const f32x16& a0, const f32x16& a1,
                                       half8& o00, half8& o01, half8& o10, half8& o11)
{
#pragma unroll
    for (int bt = 0; bt < 2; ++bt) {
        const f32x16& A = bt ? a1 : a0;
        unsigned p00 = pk2(sig2(A[0]),  sig2(A[1]));
        unsigned p01 = pk2(sig2(A[2]),  sig2(A[3]));
        unsigned p10 = pk2(sig2(A[4]),  sig2(A[5]));
        unsigned p11 = pk2(sig2(A[6]),  sig2(A[7]));
        unsigned p20 = pk2(sig2(A[8]),  sig2(A[9]));
        unsigned p21 = pk2(sig2(A[10]), sig2(A[11]));
        unsigned p30 = pk2(sig2(A[12]), sig2(A[13]));
        unsigned p31 = pk2(sig2(A[14]), sig2(A[15]));
        swapl(p00, p10); swapl(p01, p11);
        swapl(p20, p30); swapl(p21, p31);
        BU u0; u0.u[0] = p00; u0.u[1] = p01; u0.u[2] = p10; u0.u[3] = p11;
        BU u1; u1.u[0] = p20; u1.u[1] = p21; u1.u[2] = p30; u1.u[3] = p31;
        if (bt == 0) { o00 = u0.h; o01 = u1.h; }
        else         { o10 = u0.h; o11 = u1.h; }
    }
}

// One fused flow layer: Bout = sig2( Mhi*Bin (LDS) + Mlo*Bin (global) + biasK )
__device__ __forceinline__ void do_layer(const char* bufHi, const char* gLo,
                                         const half8 (&Bin)[2][8], half8 (&Bout)[2][8],
                                         const float* __restrict__ biasK,
                                         int l31, int hi)
{
    const int sw = (l31 & 15) << 4;
#pragma unroll
    for (int nt = 0; nt < 4; ++nt) {
        f4 bv0 = *(const f4*)(biasK + 32 * nt + 4 * hi);
        f4 bv1 = *(const f4*)(biasK + 32 * nt + 8 + 4 * hi);
        f4 bv2 = *(const f4*)(biasK + 32 * nt + 16 + 4 * hi);
        f4 bv3 = *(const f4*)(biasK + 32 * nt + 24 + 4 * hi);
        f32x16 a0 = { bv0[0], bv0[1], bv0[2], bv0[3],
                      bv1[0], bv1[1], bv1[2], bv1[3],
                      bv2[0], bv2[1], bv2[2], bv2[3],
                      bv3[0], bv3[1], bv3[2], bv3[3] };
        f32x16 a1 = a0;
        const char* rhi = bufHi + (nt * 32 + l31) * 256;
        const char* rlo = gLo + (nt * 32 + l31) * 256;
#pragma unroll
        for (int ks = 0; ks < 8; ++ks) {
            half8 Ah = *(const half8*)(rhi + ((ks * 32 + hi * 16) ^ sw));
            half8 Al = *(const half8*)(rlo + ks * 32 + hi * 16);
            a0 = __builtin_amdgcn_mfma_f32_32x32x16_f16(Ah, Bin[0][ks], a0, 0, 0, 0);
            a1 = __builtin_amdgcn_mfma_f32_32x32x16_f16(Ah, Bin[1][ks], a1, 0, 0, 0);
            a0 = __builtin_amdgcn_mfma_f32_32x32x16_f16(Al, Bin[0][ks], a0, 0, 0, 0);
            a1 = __builtin_amdgcn_mfma_f32_32x32x16_f16(Al, Bin[1][ks], a1, 0, 0, 0);
        }
        epi_nt(a0, a1, Bout[0][2 * nt], Bout[0][2 * nt + 1],
               Bout[1][2 * nt], Bout[1][2 * nt + 1]);
    }
}

__global__ __launch_bounds__(256, 2)
void mono_main(const float* __restrict__ x, const float* __restrict__ fy0,
               const char* __restrict__ Ghi, const char* __restrict__ Glo,
               const _Float16* __restrict__ W2hi, const _Float16* __restrict__ W2lo,
               const float* __restrict__ CgF, const float* __restrict__ b3g,
               const float* __restrict__ bLg, float* __restrict__ out)
{
    extern __shared__ __align__(16) char sm[];   // 65536: buf0 | buf1
    char* buf0 = sm;
    char* buf1 = sm + 32768;

    const int tid = threadIdx.x;
    const int lane = tid & 63, wave = tid >> 6;
    const int l31 = lane & 31, hi = lane >> 5;
    const int row0 = blockIdx.x * 256 + wave * 64;

    stage32(buf0, Ghi, tid);   // layer-0 hi; overlaps MLP
    const float b3s = b3g[0], bLs = bLg[0];

    // ---- MLP layer 1 ----
    float fy[2] = { fy0[row0 + l31], fy0[row0 + 32 + l31] };
    half8 Bm[2][4];
#pragma unroll
    for (int ks = 0; ks < 4; ++ks) {
        f4 w1a = *(const f4*)(CgF + W1P + 16 * ks + 8 * hi);
        f4 w1b = *(const f4*)(CgF + W1P + 16 * ks + 8 * hi + 4);
        f4 b1a = *(const f4*)(CgF + B1P + 16 * ks + 8 * hi);
        f4 b1b = *(const f4*)(CgF + B1P + 16 * ks + 8 * hi + 4);
#pragma unroll
        for (int bt = 0; bt < 2; ++bt) {
            BU u;
            u.u[0] = pk2(fmaxf(fy[bt] * w1a[0] + b1a[0], 0.f), fmaxf(fy[bt] * w1a[1] + b1a[1], 0.f));
            u.u[1] = pk2(fmaxf(fy[bt] * w1a[2] + b1a[2], 0.f), fmaxf(fy[bt] * w1a[3] + b1a[3], 0.f));
            u.u[2] = pk2(fmaxf(fy[bt] * w1b[0] + b1b[0], 0.f), fmaxf(fy[bt] * w1b[1] + b1b[1], 0.f));
            u.u[3] = pk2(fmaxf(fy[bt] * w1b[2] + b1b[2], 0.f), fmaxf(fy[bt] * w1b[3] + b1b[3], 0.f));
            Bm[bt][ks] = u.h;
        }
    }

    // ---- MLP layer 2 (padded 64x64, W2 split hi+lo, from global) ----
    f32x16 a00 = {}, a01 = {}, a10 = {}, a11 = {};
#pragma unroll
    for (int nt = 0; nt < 2; ++nt)
#pragma unroll
        for (int ks = 0; ks < 4; ++ks) {
            half8 Ah = *(const half8*)(W2hi + (nt * 32 + l31) * 64 + ks * 16 + hi * 8);
            half8 Al = *(const half8*)(W2lo + (nt * 32 + l31) * 64 + ks * 16 + hi * 8);
            if (nt == 0) {
                a00 = __builtin_amdgcn_mfma_f32_32x32x16_f16(Ah, Bm[0][ks], a00, 0, 0, 0);
                a10 = __builtin_amdgcn_mfma_f32_32x32x16_f16(Ah, Bm[1][ks], a10, 0, 0, 0);
                a00 = __builtin_amdgcn_mfma_f32_32x32x16_f16(Al, Bm[0][ks], a00, 0, 0, 0);
                a10 = __builtin_amdgcn_mfma_f32_32x32x16_f16(Al, Bm[1][ks], a10, 0, 0, 0);
            } else {
                a01 = __builtin_amdgcn_mfma_f32_32x32x16_f16(Ah, Bm[0][ks], a01, 0, 0, 0);
                a11 = __builtin_amdgcn_mfma_f32_32x32x16_f16(Ah, Bm[1][ks], a11, 0, 0, 0);
                a01 = __builtin_amdgcn_mfma_f32_32x32x16_f16(Al, Bm[0][ks], a01, 0, 0, 0);
                a11 = __builtin_amdgcn_mfma_f32_32x32x16_f16(Al, Bm[1][ks], a11, 0, 0, 0);
            }
        }

    // ---- MLP layer 3: theta ----
    float tp0 = 0.f, tp1 = 0.f;
#pragma unroll
    for (int nt = 0; nt < 2; ++nt)
#pragma unroll
        for (int g = 0; g < 4; ++g) {
            f4 w3 = *(const f4*)(CgF + W3P + 32 * nt + 8 * g + 4 * hi);
            f4 b2v = *(const f4*)(CgF + B2P + 32 * nt + 8 * g + 4 * hi);
            const f32x16& A0 = nt ? a01 : a00;
            const f32x16& A1 = nt ? a11 : a10;
#pragma unroll
            for (int e = 0; e < 4; ++e) {
                tp0 += w3[e] * fmaxf(A0[4 * g + e] + b2v[e], 0.f);
                tp1 += w3[e] * fmaxf(A1[4 * g + e] + b2v[e], 0.f);
            }
        }
    swaplf(tp0, tp1);
    float th = tp0 + tp1 + b3s;
    float t0 = th, t1 = th;
    swaplf(t0, t1);

    // ---- first flow layer (in=2), consts KNL-prescaled ----
    float xr[2] = { x[row0 + l31], x[row0 + 32 + l31] };
    float thv[2] = { t0, t1 };
    half8 Bq[2][8], Bp[2][8];
#pragma unroll
    for (int ks = 0; ks < 8; ++ks) {
        f4 axa = *(const f4*)(CgF + A0X + 16 * ks + 8 * hi);
        f4 axb = *(const f4*)(CgF + A0X + 16 * ks + 8 * hi + 4);
        f4 ata = *(const f4*)(CgF + A0T + 16 * ks + 8 * hi);
        f4 atb = *(const f4*)(CgF + A0T + 16 * ks + 8 * hi + 4);
        f4 b0a = *(const f4*)(CgF + B0O + 16 * ks + 8 * hi);
        f4 b0b = *(const f4*)(CgF + B0O + 16 * ks + 8 * hi + 4);
#pragma unroll
        for (int bt = 0; bt < 2; ++bt) {
            BU u;
            u.u[0] = pk2(sig2(axa[0] * xr[bt] + ata[0] * thv[bt] + b0a[0]),
                         sig2(axa[1] * xr[bt] + ata[1] * thv[bt] + b0a[1]));
            u.u[1] = pk2(sig2(axa[2] * xr[bt] + ata[2] * thv[bt] + b0a[2]),
                         sig2(axa[3] * xr[bt] + ata[3] * thv[bt] + b0a[3]));
            u.u[2] = pk2(sig2(axb[0] * xr[bt] + atb[0] * thv[bt] + b0b[0]),
                         sig2(axb[1] * xr[bt] + atb[1] * thv[bt] + b0b[1]));
            u.u[3] = pk2(sig2(axb[2] * xr[bt] + atb[2] * thv[bt] + b0b[2]),
                         sig2(axb[3] * xr[bt] + atb[3] * thv[bt] + b0b[3]));
            Bq[bt][ks] = u.h;
        }
    }
    __syncthreads();   // layer-0 hi staged

    // ---- 6 fused flow layers ----
    stage32(buf1, Ghi + 1 * 32768, tid);
    do_layer(buf0, Glo + 0 * 32768, Bq, Bp, CgF + BMO + 0 * 128, l31, hi);
    __syncthreads();
    stage32(buf0, Ghi + 2 * 32768, tid);
    do_layer(buf1, Glo + 1 * 32768, Bp, Bq, CgF + BMO + 1 * 128, l31, hi);
    __syncthreads();
    stage32(buf1, Ghi + 3 * 32768, tid);
    do_layer(buf0, Glo + 2 * 32768, Bq, Bp, CgF + BMO + 2 * 128, l31, hi);
    __syncthreads();
    stage32(buf0, Ghi + 4 * 32768, tid);
    do_layer(buf1, Glo + 3 * 32768, Bp, Bq, CgF + BMO + 3 * 128, l31, hi);
    __syncthreads();
    stage32(buf1, Ghi + 5 * 32768, tid);
    do_layer(buf0, Glo + 4 * 32768, Bq, Bp, CgF + BMO + 4 * 128, l31, hi);
    __syncthreads();
    do_layer(buf1, Glo + 5 * 32768, Bp, Bq, CgF + BMO + 5 * 128, l31, hi);

    // ---- final: out = sigmoid( vL . S6 + bL ) ----
    float d0 = 0.f, d1 = 0.f;
#pragma unroll
    for (int ks = 0; ks < 8; ++ks) {
        f4 va = *(const f4*)(CgF + VLO + 16 * ks + 8 * hi);
        f4 vb = *(const f4*)(CgF + VLO + 16 * ks + 8 * hi + 4);
        half8 s0 = Bq[0][ks], s1 = Bq[1][ks];
#pragma unroll
        for (int e = 0; e < 4; ++e) {
            d0 += va[e] * (float)s0[e] + vb[e] * (float)s0[e + 4];
            d1 += va[e] * (float)s1[e] + vb[e] * (float)s1[e + 4];
        }
    }
    swaplf(d0, d1);
    out[row0 + lane] = sigmoidf(d0 + d1 + bLs);
}

extern "C" void kernel_launch(void* const* d_in, const int* in_sizes, int n_in,
                              void* d_out, int out_size, void* d_ws, size_t ws_size,
                              hipStream_t stream)
{
    const float* x   = (const float*)d_in[0];
    const float* fy0 = (const float*)d_in[1];
    const float* u0  = (const float*)d_in[2];
    const float* w0  = (const float*)d_in[3];
    const float* la0 = (const float*)d_in[4];
    const float* b0  = (const float*)d_in[5];
    const float* uM  = (const float*)d_in[6];
    const float* wM  = (const float*)d_in[7];
    const float* laM = (const float*)d_in[8];
    const float* bM  = (const float*)d_in[9];
    const float* uL  = (const float*)d_in[10];
    // d_in[11] = wL: softmax over [1,1] == 1.0
    const float* laL = (const float*)d_in[12];
    const float* bL  = (const float*)d_in[13];
    const float* W1  = (const float*)d_in[14];
    const float* b1  = (const float*)d_in[15];
    const float* W2  = (const float*)d_in[16];
    const float* b2  = (const float*)d_in[17];
    const float* W3  = (const float*)d_in[18];
    const float* b3  = (const float*)d_in[19];
    float* out = (float*)d_out;

    char* ws = (char*)d_ws;
    char*     Ghi  = ws + GHIO;
    char*     Glo  = ws + GLOO;
    _Float16* W2hi = (_Float16*)(ws + W2HIO);
    _Float16* W2lo = (_Float16*)(ws + W2LOO);
    float*    CgF  = (float*)(ws + CGOFF);

    prep_kernel<<<97, 256, 0, stream>>>(u0, w0, la0, b0, uM, wM, laM, bM,
                                        uL, laL, W1, b1, W2, b2, W3,
                                        Ghi, Glo, W2hi, W2lo, CgF);

    static bool attr_set = false;
    if (!attr_set) {
        hipFuncSetAttribute((const void*)mono_main,
                            hipFuncAttributeMaxDynamicSharedMemorySize, 65536);
        attr_set = true;
    }
    mono_main<<<512, 256, 65536, stream>>>(x, fy0, Ghi, Glo, W2hi, W2lo,
                                           CgF, b3, bL, out);
}

// Round 8
// 160.283 us; speedup vs baseline: 1.0542x; 1.0542x over previous
//
#include <hip/hip_runtime.h>
#include <cstdint>

typedef __attribute__((ext_vector_type(8))) _Float16 half8;
typedef __attribute__((ext_vector_type(4))) _Float16 half4;
typedef __attribute__((ext_vector_type(2))) _Float16 half2v;
typedef __attribute__((ext_vector_type(16))) float f32x16;
typedef __attribute__((ext_vector_type(4))) float f4;

#define LOG2E 1.44269504088896340f
#define KNL  (-1.44269504088896340f)

__device__ __forceinline__ float fast_exp(float x) { return __builtin_amdgcn_exp2f(LOG2E * x); }
__device__ __forceinline__ float sigmoidf(float v) {
    return __builtin_amdgcn_rcpf(1.f + __builtin_amdgcn_exp2f(KNL * v));
}
// sigmoid where -log2e is already folded into the argument
__device__ __forceinline__ float sig2(float y) {
    return __builtin_amdgcn_rcpf(1.f + __builtin_amdgcn_exp2f(y));
}
// RTZ pack for ACTIVATIONS (R3 vs R4 bit-identical => activation rounding mode
// is not error-critical; weights stay exact via hi/lo split).
__device__ __forceinline__ unsigned pkz(float a, float b) {
    return __builtin_bit_cast(unsigned, __builtin_amdgcn_cvt_pkrtz(a, b));
}
__device__ __forceinline__ void swapl(unsigned& a, unsigned& b) {
    asm volatile("v_permlane32_swap_b32 %0, %1" : "+v"(a), "+v"(b));
}
__device__ __forceinline__ void swaplf(float& a, float& b) {
    asm volatile("v_permlane32_swap_b32 %0, %1" : "+v"(a), "+v"(b));
}
union BU { unsigned u[4]; half8 h; };

// CgF const region (f32 indices). A0X/A0T/B0O and BMO are KNL-prescaled.
constexpr int A0X = 0, A0T = 128, B0O = 256, BMO = 384, VLO = 1152,
              W1P = 1280, B1P = 1344, B2P = 1408, W3P = 1472, CN = 1536;

// ws byte offsets
constexpr int GOFF  = 0;                  // 6 layers x [Mhi 32KB | Mlo 32KB], swizzled
constexpr int W2HIO = 6 * 65536;          // 8192
constexpr int W2LOO = W2HIO + 8192;       // 8192
constexpr int CGOFF = W2LOO + 8192;       // CN*4

// ---------------- fused prep: 97 blocks x 256 threads ----------------
// Blocks 0..95 (l=b>>4, q=b&15): rows [8q,8q+8) of M_l = A_{l+1}*W_l, fp32,
// KNL-scaled, split fp16 hi/lo, BOTH written swizzled ((r&7)<<4).
// Block 96: vL = W6^T uLs, first-layer consts (KNL-scaled), MLP consts, W2 hi/lo.
__global__ __launch_bounds__(256)
void prep_kernel(const float* __restrict__ u0, const float* __restrict__ w0,
                 const float* __restrict__ la0, const float* __restrict__ b0,
                 const float* __restrict__ uM, const float* __restrict__ wM,
                 const float* __restrict__ laM, const float* __restrict__ bM,
                 const float* __restrict__ uL, const float* __restrict__ laL,
                 const float* __restrict__ W1, const float* __restrict__ b1,
                 const float* __restrict__ W2, const float* __restrict__ b2,
                 const float* __restrict__ W3,
                 char* __restrict__ G, _Float16* __restrict__ W2hi,
                 _Float16* __restrict__ W2lo, float* __restrict__ CgF)
{
    __shared__ float Wl[128 * 136];
    __shared__ float Al[8 * 132];
    __shared__ float uls[128];

    const int tid = threadIdx.x, b = blockIdx.x;
    const bool mblk = (b < 96);
    const int l = mblk ? (b >> 4) : 6;

    // ---- step 1: row-softmax W_l into LDS ----
    {
        const float* Wsrc = (l == 0) ? w0 : wM + (l - 1) * 16384;
        const int r = tid >> 1, h = tid & 1;
        const float* rp = Wsrc + r * 128 + h * 64;
        f4 buf[16];
#pragma unroll
        for (int v = 0; v < 16; ++v) buf[v] = *(const f4*)(rp + 4 * v);
        float mx = -1e30f;
#pragma unroll
        for (int v = 0; v < 16; ++v)
#pragma unroll
            for (int e = 0; e < 4; ++e) mx = fmaxf(mx, buf[v][e]);
        mx = fmaxf(mx, __shfl_xor(mx, 1));
        float s = 0.f;
#pragma unroll
        for (int v = 0; v < 16; ++v)
#pragma unroll
            for (int e = 0; e < 4; ++e) { buf[v][e] = fast_exp(buf[v][e] - mx); s += buf[v][e]; }
        s += __shfl_xor(s, 1);
        float inv = 1.f / s;
#pragma unroll
        for (int v = 0; v < 16; ++v)
            *(f4*)(&Wl[r * 136 + h * 64 + 4 * v]) = buf[v] * inv;
    }

    if (mblk) {
        const int q = b & 15;
        const int rl = tid >> 5, part = tid & 31;   // 8 rows x 32 threads
        const int gi = q * 8 + rl;
        // ---- step 2: A row gi = exp(laM)*softmax(uM row) ----
        {
            f4 ub = *(const f4*)(uM + (l * 128 + gi) * 128 + part * 4);
            float mx = fmaxf(fmaxf(ub[0], ub[1]), fmaxf(ub[2], ub[3]));
#pragma unroll
            for (int o = 1; o < 32; o <<= 1) mx = fmaxf(mx, __shfl_xor(mx, o));
            float s = 0.f;
#pragma unroll
            for (int e = 0; e < 4; ++e) { ub[e] = fast_exp(ub[e] - mx); s += ub[e]; }
#pragma unroll
            for (int o = 1; o < 32; o <<= 1) s += __shfl_xor(s, o);
            float sc = fast_exp(laM[l * 128 + gi]) / s;
            *(f4*)(&Al[rl * 132 + part * 4]) = ub * sc;
        }
        __syncthreads();
        // ---- step 3: 4 output cols per thread ----
        const int j0 = (tid & 31) * 4;
        f4 acc = {};
        for (int k = 0; k < 128; ++k) {
            float a = Al[rl * 132 + k];
            acc += a * *(const f4*)(&Wl[k * 136 + j0]);
        }
        // ---- step 4: KNL-scale, split hi/lo, write both swizzled ----
        const int sw = (gi & 7) << 4;
        char* bh = G + l * 65536 + gi * 256;
        char* bl = bh + 32768;
        half4 hv, lv;
#pragma unroll
        for (int e = 0; e < 4; ++e) {
            float m = KNL * acc[e];
            _Float16 hh = (_Float16)m;   // RNE — weights stay exact via hi/lo
            hv[e] = hh;
            lv[e] = (_Float16)(m - (float)hh);
        }
        *(half4*)(bh + ((2 * j0) ^ sw)) = hv;
        *(half4*)(bl + ((2 * j0) ^ sw)) = lv;
    } else {
        // ---- misc block ----
        if (tid < 64) {
            float v0 = uL[tid], v1 = uL[tid + 64];
            float mx = fmaxf(v0, v1);
#pragma unroll
            for (int o = 32; o; o >>= 1) mx = fmaxf(mx, __shfl_xor(mx, o));
            float e0 = fast_exp(v0 - mx), e1 = fast_exp(v1 - mx);
            float ssum = e0 + e1;
#pragma unroll
            for (int o = 32; o; o >>= 1) ssum += __shfl_xor(ssum, o);
            float aL = fast_exp(laL[0]) / ssum;
            uls[tid]      = e0 * aL;
            uls[tid + 64] = e1 * aL;
        }
        __syncthreads();
        if (tid < 128) {
            float s = 0.f;
            for (int k = 0; k < 128; ++k) s += uls[k] * Wl[k * 136 + tid];
            CgF[VLO + tid] = s;
        }
        if (tid < 128) {
            const int j = tid;
            float q0 = u0[2 * j], q1 = u0[2 * j + 1];
            float mx = fmaxf(q0, q1);
            float e0 = fast_exp(q0 - mx), e1 = fast_exp(q1 - mx);
            float a = fast_exp(la0[j]) / (e0 + e1);
            CgF[A0X + j] = KNL * a * e0;
            CgF[A0T + j] = KNL * a * e1;
            CgF[B0O + j] = KNL * b0[j];
        } else if (tid < 192) {
            const int t = tid - 128;
            CgF[W1P + t] = (t < 50) ? W1[t] : 0.f;
            CgF[B1P + t] = (t < 50) ? b1[t] : 0.f;
            CgF[B2P + t] = (t < 50) ? b2[t] : 0.f;
            CgF[W3P + t] = (t < 50) ? W3[t] : 0.f;
        }
        for (int i = tid; i < 768; i += 256) CgF[BMO + i] = KNL * bM[i];
        for (int i = tid; i < 4096; i += 256) {
            int r = i >> 6, c = i & 63;
            float v = (r < 50 && c < 50) ? W2[r * 50 + c] : 0.f;
            _Float16 h = (_Float16)v;
            W2hi[i] = h;
            W2lo[i] = (_Float16)(v - (float)h);
        }
    }
}

// ---------------- main ----------------
// 512 blocks x 256 threads (4 waves, 64 batch/wave), 2 INDEPENDENT blocks/CU
// (64KB LDS each): while one block stages/epilogues, the other's MFMAs run.
// Weights: single 64KB LDS buffer per block, re-staged per layer (all-LDS; R7
// showed global lo-reads stall MFMA). Activations register-resident.

__device__ __forceinline__ void stage64(char* ls, const char* gs, int tid) {
#pragma unroll
    for (int i = 0; i < 16; ++i)
        __builtin_amdgcn_global_load_lds(
            (const __attribute__((address_space(1))) unsigned*)(uintptr_t)(gs + tid * 16 + i * 4096),
            (__attribute__((address_space(3))) unsigned*)(uintptr_t)(ls + tid * 16 + i * 4096),
            16, 0, 0);
}

// acc already contains KNL*(Wx+b); sigmoid = rcp(1+exp2(acc)); RTZ pack.
__device__ __forceinline__ void epi_nt(const f32x16& a0, const f32x16& a1,
                                       half8& o00, half8& o01, half8& o10, half8& o11)
{
#pragma unroll
    for (int bt = 0; bt < 2; ++bt) {
        const f32x16& A = bt ? a1 : a0;
        unsigned p00 = pkz(sig2(A[0]),  sig2(A[1]));
        unsigned p01 = pkz(sig2(A[2]),  sig2(A[3]));
        unsigned p10 = pkz(sig2(A[4]),  sig2(A[5]));
        unsigned p11 = pkz(sig2(A[6]),  sig2(A[7]));
        unsigned p20 = pkz(sig2(A[8]),  sig2(A[9]));
        unsigned p21 = pkz(sig2(A[10]), sig2(A[11]));
        unsigned p30 = pkz(sig2(A[12]), sig2(A[13]));
        unsigned p31 = pkz(sig2(A[14]), sig2(A[15]));
        swapl(p00, p10); swapl(p01, p11);
        swapl(p20, p30); swapl(p21, p31);
        BU u0; u0.u[0] = p00; u0.u[1] = p01; u0.u[2] = p10; u0.u[3] = p11;
        BU u1; u1.u[0] = p20; u1.u[1] = p21; u1.u[2] = p30; u1.u[3] = p31;
        if (bt == 0) { o00 = u0.h; o01 = u1.h; }
        else         { o10 = u0.h; o11 = u1.h; }
    }
}

// One fused flow layer: Bout = sig2( (Mhi+Mlo)*Bin + biasK ), 4 indep MFMA
// chains per nt (even/odd-ks accumulator split) to halve dep-chain depth.
__device__ __forceinline__ void do_layer(const char* buf,
                                         const half8 (&Bin)[2][8], half8 (&Bout)[2][8],
                                         const float* __restrict__ biasK,
                                         int l31, int hi)
{
    const int sw = (l31 & 7) << 4;
#pragma unroll
    for (int nt = 0; nt < 4; ++nt) {
        f4 bv0 = *(const f4*)(biasK + 32 * nt + 4 * hi);
        f4 bv1 = *(const f4*)(biasK + 32 * nt + 8 + 4 * hi);
        f4 bv2 = *(const f4*)(biasK + 32 * nt + 16 + 4 * hi);
        f4 bv3 = *(const f4*)(biasK + 32 * nt + 24 + 4 * hi);
        f32x16 a0e = { bv0[0], bv0[1], bv0[2], bv0[3],
                       bv1[0], bv1[1], bv1[2], bv1[3],
                       bv2[0], bv2[1], bv2[2], bv2[3],
                       bv3[0], bv3[1], bv3[2], bv3[3] };
        f32x16 a1e = a0e;
        f32x16 a0o = {}, a1o = {};
        const char* rhi = buf + (nt * 32 + l31) * 256;
        const char* rlo = rhi + 32768;
        __builtin_amdgcn_s_setprio(1);
#pragma unroll
        for (int ks = 0; ks < 8; ks += 2) {
            const int offE = (ks * 32 + hi * 16) ^ sw;
            const int offO = ((ks + 1) * 32 + hi * 16) ^ sw;
            half8 AhE = *(const half8*)(rhi + offE);
            half8 AhO = *(const half8*)(rhi + offO);
            half8 AlE = *(const half8*)(rlo + offE);
            half8 AlO = *(const half8*)(rlo + offO);
            a0e = __builtin_amdgcn_mfma_f32_32x32x16_f16(AhE, Bin[0][ks],     a0e, 0, 0, 0);
            a1e = __builtin_amdgcn_mfma_f32_32x32x16_f16(AhE, Bin[1][ks],     a1e, 0, 0, 0);
            a0o = __builtin_amdgcn_mfma_f32_32x32x16_f16(AhO, Bin[0][ks + 1], a0o, 0, 0, 0);
            a1o = __builtin_amdgcn_mfma_f32_32x32x16_f16(AhO, Bin[1][ks + 1], a1o, 0, 0, 0);
            a0e = __builtin_amdgcn_mfma_f32_32x32x16_f16(AlE, Bin[0][ks],     a0e, 0, 0, 0);
            a1e = __builtin_amdgcn_mfma_f32_32x32x16_f16(AlE, Bin[1][ks],     a1e, 0, 0, 0);
            a0o = __builtin_amdgcn_mfma_f32_32x32x16_f16(AlO, Bin[0][ks + 1], a0o, 0, 0, 0);
            a1o = __builtin_amdgcn_mfma_f32_32x32x16_f16(AlO, Bin[1][ks + 1], a1o, 0, 0, 0);
        }
        __builtin_amdgcn_s_setprio(0);
        f32x16 a0 = a0e + a0o, a1 = a1e + a1o;
        epi_nt(a0, a1, Bout[0][2 * nt], Bout[0][2 * nt + 1],
               Bout[1][2 * nt], Bout[1][2 * nt + 1]);
    }
}

__global__ __launch_bounds__(256, 2)
void mono_main(const float* __restrict__ x, const float* __restrict__ fy0,
               const char* __restrict__ G,
               const _Float16* __restrict__ W2hi, const _Float16* __restrict__ W2lo,
               const float* __restrict__ CgF, const float* __restrict__ b3g,
               const float* __restrict__ bLg, float* __restrict__ out)
{
    extern __shared__ __align__(16) char sm[];   // 65536: single weight buffer

    const int tid = threadIdx.x;
    const int lane = tid & 63, wave = tid >> 6;
    const int l31 = lane & 31, hi = lane >> 5;
    const int row0 = blockIdx.x * 256 + wave * 64;

    stage64(sm, G, tid);   // layer-0 weights; overlaps MLP head
    const float b3s = b3g[0], bLs = bLg[0];

    // ---- MLP layer 1 ----
    float fy[2] = { fy0[row0 + l31], fy0[row0 + 32 + l31] };
    half8 Bm[2][4];
#pragma unroll
    for (int ks = 0; ks < 4; ++ks) {
        f4 w1a = *(const f4*)(CgF + W1P + 16 * ks + 8 * hi);
        f4 w1b = *(const f4*)(CgF + W1P + 16 * ks + 8 * hi + 4);
        f4 b1a = *(const f4*)(CgF + B1P + 16 * ks + 8 * hi);
        f4 b1b = *(const f4*)(CgF + B1P + 16 * ks + 8 * hi + 4);
#pragma unroll
        for (int bt = 0; bt < 2; ++bt) {
            BU u;
            u.u[0] = pkz(fmaxf(fy[bt] * w1a[0] + b1a[0], 0.f), fmaxf(fy[bt] * w1a[1] + b1a[1], 0.f));
            u.u[1] = pkz(fmaxf(fy[bt] * w1a[2] + b1a[2], 0.f), fmaxf(fy[bt] * w1a[3] + b1a[3], 0.f));
            u.u[2] = pkz(fmaxf(fy[bt] * w1b[0] + b1b[0], 0.f), fmaxf(fy[bt] * w1b[1] + b1b[1], 0.f));
            u.u[3] = pkz(fmaxf(fy[bt] * w1b[2] + b1b[2], 0.f), fmaxf(fy[bt] * w1b[3] + b1b[3], 0.f));
            Bm[bt][ks] = u.h;
        }
    }

    // ---- MLP layer 2 (padded 64x64, W2 hi+lo, per-lane from L2) ----
    f32x16 a00 = {}, a01 = {}, a10 = {}, a11 = {};
#pragma unroll
    for (int nt = 0; nt < 2; ++nt)
#pragma unroll
        for (int ks = 0; ks < 4; ++ks) {
            half8 Ah = *(const half8*)(W2hi + (nt * 32 + l31) * 64 + ks * 16 + hi * 8);
            half8 Al = *(const half8*)(W2lo + (nt * 32 + l31) * 64 + ks * 16 + hi * 8);
            if (nt == 0) {
                a00 = __builtin_amdgcn_mfma_f32_32x32x16_f16(Ah, Bm[0][ks], a00, 0, 0, 0);
                a10 = __builtin_amdgcn_mfma_f32_32x32x16_f16(Ah, Bm[1][ks], a10, 0, 0, 0);
                a00 = __builtin_amdgcn_mfma_f32_32x32x16_f16(Al, Bm[0][ks], a00, 0, 0, 0);
                a10 = __builtin_amdgcn_mfma_f32_32x32x16_f16(Al, Bm[1][ks], a10, 0, 0, 0);
            } else {
                a01 = __builtin_amdgcn_mfma_f32_32x32x16_f16(Ah, Bm[0][ks], a01, 0, 0, 0);
                a11 = __builtin_amdgcn_mfma_f32_32x32x16_f16(Ah, Bm[1][ks], a11, 0, 0, 0);
                a01 = __builtin_amdgcn_mfma_f32_32x32x16_f16(Al, Bm[0][ks], a01, 0, 0, 0);
                a11 = __builtin_amdgcn_mfma_f32_32x32x16_f16(Al, Bm[1][ks], a11, 0, 0, 0);
            }
        }

    // ---- MLP layer 3: theta ----
    float tp0 = 0.f, tp1 = 0.f;
#pragma unroll
    for (int nt = 0; nt < 2; ++nt)
#pragma unroll
        for (int g = 0; g < 4; ++g) {
            f4 w3 = *(const f4*)(CgF + W3P + 32 * nt + 8 * g + 4 * hi);
            f4 b2v = *(const f4*)(CgF + B2P + 32 * nt + 8 * g + 4 * hi);
            const f32x16& A0 = nt ? a01 : a00;
            const f32x16& A1 = nt ? a11 : a10;
#pragma unroll
            for (int e = 0; e < 4; ++e) {
                tp0 += w3[e] * fmaxf(A0[4 * g + e] + b2v[e], 0.f);
                tp1 += w3[e] * fmaxf(A1[4 * g + e] + b2v[e], 0.f);
            }
        }
    swaplf(tp0, tp1);
    float th = tp0 + tp1 + b3s;
    float t0 = th, t1 = th;
    swaplf(t0, t1);

    // ---- first flow layer (in=2), consts KNL-prescaled ----
    float xr[2] = { x[row0 + l31], x[row0 + 32 + l31] };
    float thv[2] = { t0, t1 };
    half8 Bq[2][8], Bp[2][8];
#pragma unroll
    for (int ks = 0; ks < 8; ++ks) {
        f4 axa = *(const f4*)(CgF + A0X + 16 * ks + 8 * hi);
        f4 axb = *(const f4*)(CgF + A0X + 16 * ks + 8 * hi + 4);
        f4 ata = *(const f4*)(CgF + A0T + 16 * ks + 8 * hi);
        f4 atb = *(const f4*)(CgF + A0T + 16 * ks + 8 * hi + 4);
        f4 b0a = *(const f4*)(CgF + B0O + 16 * ks + 8 * hi);
        f4 b0b = *(const f4*)(CgF + B0O + 16 * ks + 8 * hi + 4);
#pragma unroll
        for (int bt = 0; bt < 2; ++bt) {
            BU u;
            u.u[0] = pkz(sig2(axa[0] * xr[bt] + ata[0] * thv[bt] + b0a[0]),
                         sig2(axa[1] * xr[bt] + ata[1] * thv[bt] + b0a[1]));
            u.u[1] = pkz(sig2(axa[2] * xr[bt] + ata[2] * thv[bt] + b0a[2]),
                         sig2(axa[3] * xr[bt] + ata[3] * thv[bt] + b0a[3]));
            u.u[2] = pkz(sig2(axb[0] * xr[bt] + atb[0] * thv[bt] + b0b[0]),
                         sig2(axb[1] * xr[bt] + atb[1] * thv[bt] + b0b[1]));
            u.u[3] = pkz(sig2(axb[2] * xr[bt] + atb[2] * thv[bt] + b0b[2]),
                         sig2(axb[3] * xr[bt] + atb[3] * thv[bt] + b0b[3]));
            Bq[bt][ks] = u.h;
        }
    }
    __syncthreads();   // layer-0 staged (drains vmcnt)

    // ---- 6 fused flow layers, single buffer, re-stage per layer.
    // Per layer: compute -> barrier (all waves done with buffer) -> stage next
    // -> barrier (staged). The exposed stage latency is covered by the sibling
    // block on the same CU.
    do_layer(sm, Bq, Bp, CgF + BMO + 0 * 128, l31, hi);
    __syncthreads();
    stage64(sm, G + 1 * 65536, tid);
    __syncthreads();
    do_layer(sm, Bp, Bq, CgF + BMO + 1 * 128, l31, hi);
    __syncthreads();
    stage64(sm, G + 2 * 65536, tid);
    __syncthreads();
    do_layer(sm, Bq, Bp, CgF + BMO + 2 * 128, l31, hi);
    __syncthreads();
    stage64(sm, G + 3 * 65536, tid);
    __syncthreads();
    do_layer(sm, Bp, Bq, CgF + BMO + 3 * 128, l31, hi);
    __syncthreads();
    stage64(sm, G + 4 * 65536, tid);
    __syncthreads();
    do_layer(sm, Bq, Bp, CgF + BMO + 4 * 128, l31, hi);
    __syncthreads();
    stage64(sm, G + 5 * 65536, tid);
    __syncthreads();
    do_layer(sm, Bp, Bq, CgF + BMO + 5 * 128, l31, hi);   // S6 -> Bq

    // ---- final: out = sigmoid( vL . S6 + bL ) ----
    float d0 = 0.f, d1 = 0.f;
#pragma unroll
    for (int ks = 0; ks < 8; ++ks) {
        f4 va = *(const f4*)(CgF + VLO + 16 * ks + 8 * hi);
        f4 vb = *(const f4*)(CgF + VLO + 16 * ks + 8 * hi + 4);
        half8 s0 = Bq[0][ks], s1 = Bq[1][ks];
#pragma unroll
        for (int e = 0; e < 4; ++e) {
            d0 += va[e] * (float)s0[e] + vb[e] * (float)s0[e + 4];
            d1 += va[e] * (float)s1[e] + vb[e] * (float)s1[e + 4];
        }
    }
    swaplf(d0, d1);
    out[row0 + lane] = sigmoidf(d0 + d1 + bLs);
}

extern "C" void kernel_launch(void* const* d_in, const int* in_sizes, int n_in,
                              void* d_out, int out_size, void* d_ws, size_t ws_size,
                              hipStream_t stream)
{
    const float* x   = (const float*)d_in[0];
    const float* fy0 = (const float*)d_in[1];
    const float* u0  = (const float*)d_in[2];
    const float* w0  = (const float*)d_in[3];
    const float* la0 = (const float*)d_in[4];
    const float* b0  = (const float*)d_in[5];
    const float* uM  = (const float*)d_in[6];
    const float* wM  = (const float*)d_in[7];
    const float* laM = (const float*)d_in[8];
    const float* bM  = (const float*)d_in[9];
    const float* uL  = (const float*)d_in[10];
    // d_in[11] = wL: softmax over [1,1] == 1.0
    const float* laL = (const float*)d_in[12];
    const float* bL  = (const float*)d_in[13];
    const float* W1  = (const float*)d_in[14];
    const float* b1  = (const float*)d_in[15];
    const float* W2  = (const float*)d_in[16];
    const float* b2  = (const float*)d_in[17];
    const float* W3  = (const float*)d_in[18];
    const float* b3  = (const float*)d_in[19];
    float* out = (float*)d_out;

    char* ws = (char*)d_ws;
    char*     Gz   = ws + GOFF;
    _Float16* W2hi = (_Float16*)(ws + W2HIO);
    _Float16* W2lo = (_Float16*)(ws + W2LOO);
    float*    CgF  = (float*)(ws + CGOFF);

    prep_kernel<<<97, 256, 0, stream>>>(u0, w0, la0, b0, uM, wM, laM, bM,
                                        uL, laL, W1, b1, W2, b2, W3,
                                        Gz, W2hi, W2lo, CgF);

    static bool attr_set = false;
    if (!attr_set) {
        hipFuncSetAttribute((const void*)mono_main,
                            hipFuncAttributeMaxDynamicSharedMemorySize, 65536);
        attr_set = true;
    }
    mono_main<<<512, 256, 65536, stream>>>(x, fy0, Gz, W2hi, W2lo,
                                           CgF, b3, bL, out);
}

// Round 9
// 155.088 us; speedup vs baseline: 1.0895x; 1.0335x over previous
//
#include <hip/hip_runtime.h>
#include <cstdint>

typedef __attribute__((ext_vector_type(8))) _Float16 half8;
typedef __attribute__((ext_vector_type(4))) _Float16 half4;
typedef __attribute__((ext_vector_type(16))) float f32x16;
typedef __attribute__((ext_vector_type(4))) float f4;

#define LOG2E 1.44269504088896340f
#define KNL  (-1.44269504088896340f)

__device__ __forceinline__ float fast_exp(float x) { return __builtin_amdgcn_exp2f(LOG2E * x); }
__device__ __forceinline__ float sigmoidf(float v) {
    return __builtin_amdgcn_rcpf(1.f + __builtin_amdgcn_exp2f(KNL * v));
}
// sigmoid with -log2e prefolded into the argument
__device__ __forceinline__ float sig2(float y) {
    return __builtin_amdgcn_rcpf(1.f + __builtin_amdgcn_exp2f(y));
}
// RTZ pack for activations (R8 verified: absmax bit-identical to RNE here)
__device__ __forceinline__ unsigned pkz(float a, float b) {
    return __builtin_bit_cast(unsigned, __builtin_amdgcn_cvt_pkrtz(a, b));
}
__device__ __forceinline__ void swapl(unsigned& a, unsigned& b) {
    asm volatile("v_permlane32_swap_b32 %0, %1" : "+v"(a), "+v"(b));
}
__device__ __forceinline__ void swaplf(float& a, float& b) {
    asm volatile("v_permlane32_swap_b32 %0, %1" : "+v"(a), "+v"(b));
}
union BU { unsigned u[4]; half8 h; };

// CgF const region (f32 indices). A0X/A0T/B0O and BMO are KNL-prescaled.
constexpr int A0X = 0, A0T = 128, B0O = 256, BMO = 384, VLO = 1152,
              W1P = 1280, B1P = 1344, B2P = 1408, W3P = 1472, CN = 1536;

// ws byte offsets
constexpr int GOFF  = 0;                  // 6 layers x [Mhi 32KB | Mlo 32KB], swizzled
constexpr int W2HIO = 6 * 65536;          // 8192
constexpr int W2LOO = W2HIO + 8192;       // 8192
constexpr int CGOFF = W2LOO + 8192;       // CN*4

// ---------------- fused prep: 97 blocks x 256 threads (R8, verified) --------
__global__ __launch_bounds__(256)
void prep_kernel(const float* __restrict__ u0, const float* __restrict__ w0,
                 const float* __restrict__ la0, const float* __restrict__ b0,
                 const float* __restrict__ uM, const float* __restrict__ wM,
                 const float* __restrict__ laM, const float* __restrict__ bM,
                 const float* __restrict__ uL, const float* __restrict__ laL,
                 const float* __restrict__ W1, const float* __restrict__ b1,
                 const float* __restrict__ W2, const float* __restrict__ b2,
                 const float* __restrict__ W3,
                 char* __restrict__ G, _Float16* __restrict__ W2hi,
                 _Float16* __restrict__ W2lo, float* __restrict__ CgF)
{
    __shared__ float Wl[128 * 136];
    __shared__ float Al[8 * 132];
    __shared__ float uls[128];

    const int tid = threadIdx.x, b = blockIdx.x;
    const bool mblk = (b < 96);
    const int l = mblk ? (b >> 4) : 6;

    // ---- step 1: row-softmax W_l into LDS ----
    {
        const float* Wsrc = (l == 0) ? w0 : wM + (l - 1) * 16384;
        const int r = tid >> 1, h = tid & 1;
        const float* rp = Wsrc + r * 128 + h * 64;
        f4 buf[16];
#pragma unroll
        for (int v = 0; v < 16; ++v) buf[v] = *(const f4*)(rp + 4 * v);
        float mx = -1e30f;
#pragma unroll
        for (int v = 0; v < 16; ++v)
#pragma unroll
            for (int e = 0; e < 4; ++e) mx = fmaxf(mx, buf[v][e]);
        mx = fmaxf(mx, __shfl_xor(mx, 1));
        float s = 0.f;
#pragma unroll
        for (int v = 0; v < 16; ++v)
#pragma unroll
            for (int e = 0; e < 4; ++e) { buf[v][e] = fast_exp(buf[v][e] - mx); s += buf[v][e]; }
        s += __shfl_xor(s, 1);
        float inv = 1.f / s;
#pragma unroll
        for (int v = 0; v < 16; ++v)
            *(f4*)(&Wl[r * 136 + h * 64 + 4 * v]) = buf[v] * inv;
    }

    if (mblk) {
        const int q = b & 15;
        const int rl = tid >> 5, part = tid & 31;   // 8 rows x 32 threads
        const int gi = q * 8 + rl;
        // ---- step 2: A row gi = exp(laM)*softmax(uM row) ----
        {
            f4 ub = *(const f4*)(uM + (l * 128 + gi) * 128 + part * 4);
            float mx = fmaxf(fmaxf(ub[0], ub[1]), fmaxf(ub[2], ub[3]));
#pragma unroll
            for (int o = 1; o < 32; o <<= 1) mx = fmaxf(mx, __shfl_xor(mx, o));
            float s = 0.f;
#pragma unroll
            for (int e = 0; e < 4; ++e) { ub[e] = fast_exp(ub[e] - mx); s += ub[e]; }
#pragma unroll
            for (int o = 1; o < 32; o <<= 1) s += __shfl_xor(s, o);
            float sc = fast_exp(laM[l * 128 + gi]) / s;
            *(f4*)(&Al[rl * 132 + part * 4]) = ub * sc;
        }
        __syncthreads();
        // ---- step 3: 4 output cols per thread ----
        const int j0 = (tid & 31) * 4;
        f4 acc = {};
        for (int k = 0; k < 128; ++k) {
            float a = Al[rl * 132 + k];
            acc += a * *(const f4*)(&Wl[k * 136 + j0]);
        }
        // ---- step 4: KNL-scale, split hi/lo, write both swizzled ----
        const int sw = (gi & 7) << 4;
        char* bh = G + l * 65536 + gi * 256;
        char* bl = bh + 32768;
        half4 hv, lv;
#pragma unroll
        for (int e = 0; e < 4; ++e) {
            float m = KNL * acc[e];
            _Float16 hh = (_Float16)m;   // RNE — weights exact via hi/lo
            hv[e] = hh;
            lv[e] = (_Float16)(m - (float)hh);
        }
        *(half4*)(bh + ((2 * j0) ^ sw)) = hv;
        *(half4*)(bl + ((2 * j0) ^ sw)) = lv;
    } else {
        // ---- misc block ----
        if (tid < 64) {
            float v0 = uL[tid], v1 = uL[tid + 64];
            float mx = fmaxf(v0, v1);
#pragma unroll
            for (int o = 32; o; o >>= 1) mx = fmaxf(mx, __shfl_xor(mx, o));
            float e0 = fast_exp(v0 - mx), e1 = fast_exp(v1 - mx);
            float ssum = e0 + e1;
#pragma unroll
            for (int o = 32; o; o >>= 1) ssum += __shfl_xor(ssum, o);
            float aL = fast_exp(laL[0]) / ssum;
            uls[tid]      = e0 * aL;
            uls[tid + 64] = e1 * aL;
        }
        __syncthreads();
        if (tid < 128) {
            float s = 0.f;
            for (int k = 0; k < 128; ++k) s += uls[k] * Wl[k * 136 + tid];
            CgF[VLO + tid] = s;
        }
        if (tid < 128) {
            const int j = tid;
            float q0 = u0[2 * j], q1 = u0[2 * j + 1];
            float mx = fmaxf(q0, q1);
            float e0 = fast_exp(q0 - mx), e1 = fast_exp(q1 - mx);
            float a = fast_exp(la0[j]) / (e0 + e1);
            CgF[A0X + j] = KNL * a * e0;
            CgF[A0T + j] = KNL * a * e1;
            CgF[B0O + j] = KNL * b0[j];
        } else if (tid < 192) {
            const int t = tid - 128;
            CgF[W1P + t] = (t < 50) ? W1[t] : 0.f;
            CgF[B1P + t] = (t < 50) ? b1[t] : 0.f;
            CgF[B2P + t] = (t < 50) ? b2[t] : 0.f;
            CgF[W3P + t] = (t < 50) ? W3[t] : 0.f;
        }
        for (int i = tid; i < 768; i += 256) CgF[BMO + i] = KNL * bM[i];
        for (int i = tid; i < 4096; i += 256) {
            int r = i >> 6, c = i & 63;
            float v = (r < 50 && c < 50) ? W2[r * 50 + c] : 0.f;
            _Float16 h = (_Float16)v;
            W2hi[i] = h;
            W2lo[i] = (_Float16)(v - (float)h);
        }
    }
}

// ---------------- main ----------------
// R6 schedule: 256 blocks x 512 threads (8 waves, 64 batch/wave), 1 block/CU,
// 128KB LDS = 2 x 64KB [Mhi|Mlo] double-buffer, stage issued one FULL layer
// ahead (R8's between-barriers staging regressed; R7's global lo regressed).
// R8 micro-opts: even/odd MFMA chains, setprio, bias-in-acc, RTZ pack.

__device__ __forceinline__ void stage64(char* ls, const char* gs, int tid) {
#pragma unroll
    for (int i = 0; i < 8; ++i)
        __builtin_amdgcn_global_load_lds(
            (const __attribute__((address_space(1))) unsigned*)(uintptr_t)(gs + tid * 16 + i * 8192),
            (__attribute__((address_space(3))) unsigned*)(uintptr_t)(ls + tid * 16 + i * 8192),
            16, 0, 0);
}

// acc already contains KNL*(Wx+b); sigmoid = rcp(1+exp2(acc)); RTZ pack.
__device__ __forceinline__ void epi_nt(const f32x16& a0, const f32x16& a1,
                                       half8& o00, half8& o01, half8& o10, half8& o11)
{
#pragma unroll
    for (int bt = 0; bt < 2; ++bt) {
        const f32x16& A = bt ? a1 : a0;
        unsigned p00 = pkz(sig2(A[0]),  sig2(A[1]));
        unsigned p01 = pkz(sig2(A[2]),  sig2(A[3]));
        unsigned p10 = pkz(sig2(A[4]),  sig2(A[5]));
        unsigned p11 = pkz(sig2(A[6]),  sig2(A[7]));
        unsigned p20 = pkz(sig2(A[8]),  sig2(A[9]));
        unsigned p21 = pkz(sig2(A[10]), sig2(A[11]));
        unsigned p30 = pkz(sig2(A[12]), sig2(A[13]));
        unsigned p31 = pkz(sig2(A[14]), sig2(A[15]));
        swapl(p00, p10); swapl(p01, p11);
        swapl(p20, p30); swapl(p21, p31);
        BU u0; u0.u[0] = p00; u0.u[1] = p01; u0.u[2] = p10; u0.u[3] = p11;
        BU u1; u1.u[0] = p20; u1.u[1] = p21; u1.u[2] = p30; u1.u[3] = p31;
        if (bt == 0) { o00 = u0.h; o01 = u1.h; }
        else         { o10 = u0.h; o11 = u1.h; }
    }
}

// One fused flow layer: Bout = sig2( (Mhi+Mlo)*Bin + biasK ), even/odd chains.
__device__ __forceinline__ void do_layer(const char* buf,
                                         const half8 (&Bin)[2][8], half8 (&Bout)[2][8],
                                         const float* __restrict__ biasK,
                                         int l31, int hi)
{
    const int sw = (l31 & 7) << 4;
#pragma unroll
    for (int nt = 0; nt < 4; ++nt) {
        f4 bv0 = *(const f4*)(biasK + 32 * nt + 4 * hi);
        f4 bv1 = *(const f4*)(biasK + 32 * nt + 8 + 4 * hi);
        f4 bv2 = *(const f4*)(biasK + 32 * nt + 16 + 4 * hi);
        f4 bv3 = *(const f4*)(biasK + 32 * nt + 24 + 4 * hi);
        f32x16 a0e = { bv0[0], bv0[1], bv0[2], bv0[3],
                       bv1[0], bv1[1], bv1[2], bv1[3],
                       bv2[0], bv2[1], bv2[2], bv2[3],
                       bv3[0], bv3[1], bv3[2], bv3[3] };
        f32x16 a1e = a0e;
        f32x16 a0o = {}, a1o = {};
        const char* rhi = buf + (nt * 32 + l31) * 256;
        const char* rlo = rhi + 32768;
        __builtin_amdgcn_s_setprio(1);
#pragma unroll
        for (int ks = 0; ks < 8; ks += 2) {
            const int offE = (ks * 32 + hi * 16) ^ sw;
            const int offO = ((ks + 1) * 32 + hi * 16) ^ sw;
            half8 AhE = *(const half8*)(rhi + offE);
            half8 AhO = *(const half8*)(rhi + offO);
            half8 AlE = *(const half8*)(rlo + offE);
            half8 AlO = *(const half8*)(rlo + offO);
            a0e = __builtin_amdgcn_mfma_f32_32x32x16_f16(AhE, Bin[0][ks],     a0e, 0, 0, 0);
            a1e = __builtin_amdgcn_mfma_f32_32x32x16_f16(AhE, Bin[1][ks],     a1e, 0, 0, 0);
            a0o = __builtin_amdgcn_mfma_f32_32x32x16_f16(AhO, Bin[0][ks + 1], a0o, 0, 0, 0);
            a1o = __builtin_amdgcn_mfma_f32_32x32x16_f16(AhO, Bin[1][ks + 1], a1o, 0, 0, 0);
            a0e = __builtin_amdgcn_mfma_f32_32x32x16_f16(AlE, Bin[0][ks],     a0e, 0, 0, 0);
            a1e = __builtin_amdgcn_mfma_f32_32x32x16_f16(AlE, Bin[1][ks],     a1e, 0, 0, 0);
            a0o = __builtin_amdgcn_mfma_f32_32x32x16_f16(AlO, Bin[0][ks + 1], a0o, 0, 0, 0);
            a1o = __builtin_amdgcn_mfma_f32_32x32x16_f16(AlO, Bin[1][ks + 1], a1o, 0, 0, 0);
        }
        __builtin_amdgcn_s_setprio(0);
        f32x16 a0 = a0e + a0o, a1 = a1e + a1o;
        epi_nt(a0, a1, Bout[0][2 * nt], Bout[0][2 * nt + 1],
               Bout[1][2 * nt], Bout[1][2 * nt + 1]);
    }
}

__global__ __launch_bounds__(512, 2)
void mono_main(const float* __restrict__ x, const float* __restrict__ fy0,
               const char* __restrict__ G,
               const _Float16* __restrict__ W2hi, const _Float16* __restrict__ W2lo,
               const float* __restrict__ CgF, const float* __restrict__ b3g,
               const float* __restrict__ bLg, float* __restrict__ out)
{
    extern __shared__ __align__(16) char sm[];   // 131072: buf0 | buf1
    char* buf0 = sm;
    char* buf1 = sm + 65536;

    const int tid = threadIdx.x;
    const int lane = tid & 63, wave = tid >> 6;
    const int l31 = lane & 31, hi = lane >> 5;
    const int row0 = blockIdx.x * 512 + wave * 64;

    stage64(buf0, G, tid);   // layer-0 weights; overlaps MLP head
    const float b3s = b3g[0], bLs = bLg[0];

    // ---- MLP layer 1 ----
    float fy[2] = { fy0[row0 + l31], fy0[row0 + 32 + l31] };
    half8 Bm[2][4];
#pragma unroll
    for (int ks = 0; ks < 4; ++ks) {
        f4 w1a = *(const f4*)(CgF + W1P + 16 * ks + 8 * hi);
        f4 w1b = *(const f4*)(CgF + W1P + 16 * ks + 8 * hi + 4);
        f4 b1a = *(const f4*)(CgF + B1P + 16 * ks + 8 * hi);
        f4 b1b = *(const f4*)(CgF + B1P + 16 * ks + 8 * hi + 4);
#pragma unroll
        for (int bt = 0; bt < 2; ++bt) {
            BU u;
            u.u[0] = pkz(fmaxf(fy[bt] * w1a[0] + b1a[0], 0.f), fmaxf(fy[bt] * w1a[1] + b1a[1], 0.f));
            u.u[1] = pkz(fmaxf(fy[bt] * w1a[2] + b1a[2], 0.f), fmaxf(fy[bt] * w1a[3] + b1a[3], 0.f));
            u.u[2] = pkz(fmaxf(fy[bt] * w1b[0] + b1b[0], 0.f), fmaxf(fy[bt] * w1b[1] + b1b[1], 0.f));
            u.u[3] = pkz(fmaxf(fy[bt] * w1b[2] + b1b[2], 0.f), fmaxf(fy[bt] * w1b[3] + b1b[3], 0.f));
            Bm[bt][ks] = u.h;
        }
    }

    // ---- MLP layer 2 (padded 64x64, W2 hi+lo, per-lane from L2) ----
    f32x16 a00 = {}, a01 = {}, a10 = {}, a11 = {};
#pragma unroll
    for (int nt = 0; nt < 2; ++nt)
#pragma unroll
        for (int ks = 0; ks < 4; ++ks) {
            half8 Ah = *(const half8*)(W2hi + (nt * 32 + l31) * 64 + ks * 16 + hi * 8);
            half8 Al = *(const half8*)(W2lo + (nt * 32 + l31) * 64 + ks * 16 + hi * 8);
            if (nt == 0) {
                a00 = __builtin_amdgcn_mfma_f32_32x32x16_f16(Ah, Bm[0][ks], a00, 0, 0, 0);
                a10 = __builtin_amdgcn_mfma_f32_32x32x16_f16(Ah, Bm[1][ks], a10, 0, 0, 0);
                a00 = __builtin_amdgcn_mfma_f32_32x32x16_f16(Al, Bm[0][ks], a00, 0, 0, 0);
                a10 = __builtin_amdgcn_mfma_f32_32x32x16_f16(Al, Bm[1][ks], a10, 0, 0, 0);
            } else {
                a01 = __builtin_amdgcn_mfma_f32_32x32x16_f16(Ah, Bm[0][ks], a01, 0, 0, 0);
                a11 = __builtin_amdgcn_mfma_f32_32x32x16_f16(Ah, Bm[1][ks], a11, 0, 0, 0);
                a01 = __builtin_amdgcn_mfma_f32_32x32x16_f16(Al, Bm[0][ks], a01, 0, 0, 0);
                a11 = __builtin_amdgcn_mfma_f32_32x32x16_f16(Al, Bm[1][ks], a11, 0, 0, 0);
            }
        }

    // ---- MLP layer 3: theta ----
    float tp0 = 0.f, tp1 = 0.f;
#pragma unroll
    for (int nt = 0; nt < 2; ++nt)
#pragma unroll
        for (int g = 0; g < 4; ++g) {
            f4 w3 = *(const f4*)(CgF + W3P + 32 * nt + 8 * g + 4 * hi);
            f4 b2v = *(const f4*)(CgF + B2P + 32 * nt + 8 * g + 4 * hi);
            const f32x16& A0 = nt ? a01 : a00;
            const f32x16& A1 = nt ? a11 : a10;
#pragma unroll
            for (int e = 0; e < 4; ++e) {
                tp0 += w3[e] * fmaxf(A0[4 * g + e] + b2v[e], 0.f);
                tp1 += w3[e] * fmaxf(A1[4 * g + e] + b2v[e], 0.f);
            }
        }
    swaplf(tp0, tp1);
    float th = tp0 + tp1 + b3s;
    float t0 = th, t1 = th;
    swaplf(t0, t1);

    // ---- first flow layer (in=2), consts KNL-prescaled ----
    float xr[2] = { x[row0 + l31], x[row0 + 32 + l31] };
    float thv[2] = { t0, t1 };
    half8 Bq[2][8], Bp[2][8];
#pragma unroll
    for (int ks = 0; ks < 8; ++ks) {
        f4 axa = *(const f4*)(CgF + A0X + 16 * ks + 8 * hi);
        f4 axb = *(const f4*)(CgF + A0X + 16 * ks + 8 * hi + 4);
        f4 ata = *(const f4*)(CgF + A0T + 16 * ks + 8 * hi);
        f4 atb = *(const f4*)(CgF + A0T + 16 * ks + 8 * hi + 4);
        f4 b0a = *(const f4*)(CgF + B0O + 16 * ks + 8 * hi);
        f4 b0b = *(const f4*)(CgF + B0O + 16 * ks + 8 * hi + 4);
#pragma unroll
        for (int bt = 0; bt < 2; ++bt) {
            BU u;
            u.u[0] = pkz(sig2(axa[0] * xr[bt] + ata[0] * thv[bt] + b0a[0]),
                         sig2(axa[1] * xr[bt] + ata[1] * thv[bt] + b0a[1]));
            u.u[1] = pkz(sig2(axa[2] * xr[bt] + ata[2] * thv[bt] + b0a[2]),
                         sig2(axa[3] * xr[bt] + ata[3] * thv[bt] + b0a[3]));
            u.u[2] = pkz(sig2(axb[0] * xr[bt] + atb[0] * thv[bt] + b0b[0]),
                         sig2(axb[1] * xr[bt] + atb[1] * thv[bt] + b0b[1]));
            u.u[3] = pkz(sig2(axb[2] * xr[bt] + atb[2] * thv[bt] + b0b[2]),
                         sig2(axb[3] * xr[bt] + atb[3] * thv[bt] + b0b[3]));
            Bq[bt][ks] = u.h;
        }
    }
    __syncthreads();   // layer-0 staged

    // ---- 6 fused flow layers, dbuf ping-pong, prefetch 1 layer ahead ----
    stage64(buf1, G + 1 * 65536, tid);
    do_layer(buf0, Bq, Bp, CgF + BMO + 0 * 128, l31, hi);
    __syncthreads();
    stage64(buf0, G + 2 * 65536, tid);
    do_layer(buf1, Bp, Bq, CgF + BMO + 1 * 128, l31, hi);
    __syncthreads();
    stage64(buf1, G + 3 * 65536, tid);
    do_layer(buf0, Bq, Bp, CgF + BMO + 2 * 128, l31, hi);
    __syncthreads();
    stage64(buf0, G + 4 * 65536, tid);
    do_layer(buf1, Bp, Bq, CgF + BMO + 3 * 128, l31, hi);
    __syncthreads();
    stage64(buf1, G + 5 * 65536, tid);
    do_layer(buf0, Bq, Bp, CgF + BMO + 4 * 128, l31, hi);
    __syncthreads();
    do_layer(buf1, Bp, Bq, CgF + BMO + 5 * 128, l31, hi);   // S6 -> Bq

    // ---- final: out = sigmoid( vL . S6 + bL ) ----
    float d0 = 0.f, d1 = 0.f;
#pragma unroll
    for (int ks = 0; ks < 8; ++ks) {
        f4 va = *(const f4*)(CgF + VLO + 16 * ks + 8 * hi);
        f4 vb = *(const f4*)(CgF + VLO + 16 * ks + 8 * hi + 4);
        half8 s0 = Bq[0][ks], s1 = Bq[1][ks];
#pragma unroll
        for (int e = 0; e < 4; ++e) {
            d0 += va[e] * (float)s0[e] + vb[e] * (float)s0[e + 4];
            d1 += va[e] * (float)s1[e] + vb[e] * (float)s1[e + 4];
        }
    }
    swaplf(d0, d1);
    out[row0 + lane] = sigmoidf(d0 + d1 + bLs);
}

extern "C" void kernel_launch(void* const* d_in, const int* in_sizes, int n_in,
                              void* d_out, int out_size, void* d_ws, size_t ws_size,
                              hipStream_t stream)
{
    const float* x   = (const float*)d_in[0];
    const float* fy0 = (const float*)d_in[1];
    const float* u0  = (const float*)d_in[2];
    const float* w0  = (const float*)d_in[3];
    const float* la0 = (const float*)d_in[4];
    const float* b0  = (const float*)d_in[5];
    const float* uM  = (const float*)d_in[6];
    const float* wM  = (const float*)d_in[7];
    const float* laM = (const float*)d_in[8];
    const float* bM  = (const float*)d_in[9];
    const float* uL  = (const float*)d_in[10];
    // d_in[11] = wL: softmax over [1,1] == 1.0
    const float* laL = (const float*)d_in[12];
    const float* bL  = (const float*)d_in[13];
    const float* W1  = (const float*)d_in[14];
    const float* b1  = (const float*)d_in[15];
    const float* W2  = (const float*)d_in[16];
    const float* b2  = (const float*)d_in[17];
    const float* W3  = (const float*)d_in[18];
    const float* b3  = (const float*)d_in[19];
    float* out = (float*)d_out;

    char* ws = (char*)d_ws;
    char*     Gz   = ws + GOFF;
    _Float16* W2hi = (_Float16*)(ws + W2HIO);
    _Float16* W2lo = (_Float16*)(ws + W2LOO);
    float*    CgF  = (float*)(ws + CGOFF);

    prep_kernel<<<97, 256, 0, stream>>>(u0, w0, la0, b0, uM, wM, laM, bM,
                                        uL, laL, W1, b1, W2, b2, W3,
                                        Gz, W2hi, W2lo, CgF);

    static bool attr_set = false;
    if (!attr_set) {
        hipFuncSetAttribute((const void*)mono_main,
                            hipFuncAttributeMaxDynamicSharedMemorySize, 131072);
        attr_set = true;
    }
    mono_main<<<256, 512, 131072, stream>>>(x, fy0, Gz, W2hi, W2lo,
                                            CgF, b3, bL, out);
}